// Round 5
// baseline (731.388 us; speedup 1.0000x reference)
//
#include <hip/hip_runtime.h>
#include <hip/hip_bf16.h>
#include <math.h>

#define BATCH 16
#define SEQ   512
#define DC    1024
#define DP    64
#define NT    8
#define DH    4096
#define NTOK  (BATCH*SEQ)   // 8192

#define BM 128
#define BN 128
#define BK 32

typedef __attribute__((ext_vector_type(8))) short short8;        // 8 bf16
typedef __attribute__((ext_vector_type(4))) float floatx4;       // MFMA acc
typedef __attribute__((ext_vector_type(4))) unsigned short ushort4v;
typedef __attribute__((ext_vector_type(8))) unsigned short ushort8v;

__device__ __forceinline__ unsigned short f2bf(float f) {
  union { float f; unsigned u; } v; v.f = f;
  unsigned r = v.u + 0x7FFFu + ((v.u >> 16) & 1u);   // round-to-nearest-even
  return (unsigned short)(r >> 16);
}

// async global -> LDS, 16B per lane, LDS dst = uniform base + lane*16
__device__ __forceinline__ void gl_lds16(const void* g, void* l) {
  __builtin_amdgcn_global_load_lds(
      (__attribute__((address_space(1))) void*)g,
      (__attribute__((address_space(3))) void*)l, 16, 0, 0);
}

// ---------------- routing: one wave per token (also writes bf16 copy of x) ----
__global__ __launch_bounds__(256) void route_kernel(
    const float* __restrict__ x, const float* __restrict__ pe,
    const float* __restrict__ pwp, const float* __restrict__ cwp,
    const float* __restrict__ pos_sigs, const float* __restrict__ csigs,
    int* __restrict__ counts, int* __restrict__ list,
    unsigned short* __restrict__ xb) {
  int wid  = threadIdx.x >> 6;
  int lane = threadIdx.x & 63;
  int token = blockIdx.x * 4 + wid;
  int s = token & (SEQ - 1);

  float pwr = 1.f / (1.f + expf(-pwp[0]));
  float cwr = 1.f / (1.f + expf(-cwp[0]));
  float tot = pwr + cwr;
  float pw = pwr / tot, cw = cwr / tot;

  float acc[NT];
#pragma unroll
  for (int t = 0; t < NT; t++) acc[t] = 0.f;

  float a0 = pw * pe[s * DP + lane];
#pragma unroll
  for (int t = 0; t < NT; t++) {
    float v = pos_sigs[t * DP + lane];
    float sg = (v > 0.f) ? 1.f : ((v < 0.f) ? -1.f : 0.f);
    acc[t] = fmaf(a0, sg, acc[t]);
  }

  const float* xrow = x + (size_t)token * DC;
  unsigned short* xbrow = xb + (size_t)token * DC;
#pragma unroll 4
  for (int i = 0; i < DC / 64; i++) {
    int c = lane + i * 64;
    float xv = xrow[c];
    xbrow[c] = f2bf(xv);
    float a = cw * xv;
#pragma unroll
    for (int t = 0; t < NT; t++) {
      float v = csigs[t * DC + c];
      float sg = (v > 0.f) ? 1.f : ((v < 0.f) ? -1.f : 0.f);
      acc[t] = fmaf(a, sg, acc[t]);
    }
  }

#pragma unroll
  for (int off = 32; off >= 1; off >>= 1)
#pragma unroll
    for (int t = 0; t < NT; t++) acc[t] += __shfl_xor(acc[t], off);

  if (lane == 0) {
    int best = 0; float bv = acc[0];
#pragma unroll
    for (int t = 1; t < NT; t++)
      if (acc[t] > bv) { bv = acc[t]; best = t; }
    int slot = atomicAdd(&counts[best], 1);
    list[best * NTOK + slot] = token;
  }
}

// ------------- transpose+convert: in [AR][AC] fp32 -> out [AC][AR] bf16 ------
template<int AR, int AC>
__global__ __launch_bounds__(256) void transpose_kernel(
    const float* __restrict__ in, unsigned short* __restrict__ out) {
  __shared__ unsigned short tile[64 * 65];
  int t = blockIdx.z;
  const float* in_t = in + (size_t)t * AR * AC;
  unsigned short* out_t = out + (size_t)t * AR * AC;
  int x0 = blockIdx.x * 64, y0 = blockIdx.y * 64;
  int tid = threadIdx.x;
  int ry = tid >> 2, cx = (tid & 3) * 16;
  const float* src = in_t + (size_t)(y0 + ry) * AC + x0 + cx;
  float4 v0 = *(const float4*)(src);
  float4 v1 = *(const float4*)(src + 4);
  float4 v2 = *(const float4*)(src + 8);
  float4 v3 = *(const float4*)(src + 12);
  unsigned short* trow = &tile[ry * 65 + cx];
  trow[0]  = f2bf(v0.x); trow[1]  = f2bf(v0.y); trow[2]  = f2bf(v0.z); trow[3]  = f2bf(v0.w);
  trow[4]  = f2bf(v1.x); trow[5]  = f2bf(v1.y); trow[6]  = f2bf(v1.z); trow[7]  = f2bf(v1.w);
  trow[8]  = f2bf(v2.x); trow[9]  = f2bf(v2.y); trow[10] = f2bf(v2.z); trow[11] = f2bf(v2.w);
  trow[12] = f2bf(v3.x); trow[13] = f2bf(v3.y); trow[14] = f2bf(v3.z); trow[15] = f2bf(v3.w);
  __syncthreads();
  int rx = tid >> 2, cy = (tid & 3) * 16;
  ushort8v o0, o1;
#pragma unroll
  for (int j = 0; j < 8; j++) o0[j] = tile[(cy + j) * 65 + rx];
#pragma unroll
  for (int j = 0; j < 8; j++) o1[j] = tile[(cy + 8 + j) * 65 + rx];
  size_t ob = (size_t)(x0 + rx) * AR + y0 + cy;
  *(ushort8v*)&out_t[ob]     = o0;
  *(ushort8v*)&out_t[ob + 8] = o1;
}

// ====== gemm1: 256x256 tile, BK=64, 8 waves, 4-phase interleaved schedule ====
// Port of the 8-phase template (T2+T3+T4+T5): per K-tile, 4 phases of
// {ds_read subtile || 2x global_load_lds -> s_barrier -> lgkmcnt(0) ->
//  setprio(1) 16 MFMA setprio(0) -> s_barrier}; vmcnt drained ONCE per K-tile
// (end of phase 3), never per-phase. Double-buffered 128KB LDS, 1 block/CU.
// Wave tile 128x64 -> LDS intensity 43 FLOP/B (vs 32 at 64x64).
//
// Swizzle (T2, rule 21 both-sides): physical 16B chunk p of row r holds source
// chunk p ^ (r&7). Stage side: linear LDS dst + pre-swizzled global source
// (sw = ((tid&7) ^ ((tid>>3)&7))*8). Read side: chunk = (kk*4+quad) ^ (l15&7).
// Aggregate-uniform 8 lanes per 16B bank-slot -> conflict-free b128 reads.
template<int K, int N, bool GELU>
__global__ __launch_bounds__(512) void gemm8p_kernel(
    const unsigned short* __restrict__ A, const unsigned short* __restrict__ BT,
    const float* __restrict__ bias, const int* __restrict__ counts,
    const int* __restrict__ list, unsigned short* __restrict__ Hout,
    float* __restrict__ Fout) {
  int t = blockIdx.z;
  int count = counts[t];
  int base = blockIdx.y * 256;
  if (base >= count) return;
  int j0 = blockIdx.x * 256;

  __shared__ __align__(16) unsigned short As[2][256 * 64];  // 2 x 32 KB
  __shared__ __align__(16) unsigned short Bs[2][256 * 64];  // 2 x 32 KB
  __shared__ int toks[256];

  int tid = threadIdx.x;
  if (tid < 256) {
    int slot = base + tid;
    toks[tid] = (slot < count) ? list[t * NTOK + slot] : -1;
  }
  __syncthreads();

  // ---- staging geometry: 8 loads/thread/K-tile; load i<4 = A slab i (64 rows),
  // i>=4 = B slab i-4. Thread covers row = slab*64 + (tid>>3), chunk tid&7.
  int srow = tid >> 3;                               // 0..63 within slab
  int sw = (((tid & 7) ^ (srow & 7)) << 3);          // pre-swizzled source k-elems
  const unsigned short* gsrcA[4];
  const unsigned short* gsrcB[4];
#pragma unroll
  for (int i = 0; i < 4; i++) {
    int ra = i * 64 + srow;
    int tk = toks[ra]; if (tk < 0) tk = 0;           // garbage rows, never written
    gsrcA[i] = A + (size_t)tk * K + sw;
    gsrcB[i] = BT + ((size_t)t * N + (size_t)(j0 + ra)) * K + sw;
  }
  int ldst = tid * 8;                                // elems; slab-linear lane*16B

  // ---- fragment geometry: 8 waves = 2 (rows) x 4 (cols); wave tile 128x64
  int w = tid >> 6;
  int wr = w >> 2, wc = w & 3;
  int lane = tid & 63;
  int quad = lane >> 4, l15 = lane & 15;
  int axor = l15 & 7;
  int abase = (wr * 128 + l15) * 64;                 // elem offset of (row, chunk0)
  int bbase = (wc * 64 + l15) * 64;
  int koff0 = ((0 * 4 + quad) ^ axor) << 3;          // kk=0 chunk, elems
  int koff1 = ((1 * 4 + quad) ^ axor) << 3;          // kk=1 chunk, elems

  floatx4 acc[8][4];
#pragma unroll
  for (int m = 0; m < 8; m++)
#pragma unroll
    for (int ni = 0; ni < 4; ni++) acc[m][ni] = (floatx4){0.f, 0.f, 0.f, 0.f};

  constexpr int NKT = K / 64;

  // prologue: stage K-tile 0 into buf 0, drain, barrier
#pragma unroll
  for (int i = 0; i < 4; i++) {
    gl_lds16(gsrcA[i], &As[0][i * 4096 + ldst]);
    gl_lds16(gsrcB[i], &Bs[0][i * 4096 + ldst]);
    gsrcA[i] += 64; gsrcB[i] += 64;
  }
  asm volatile("s_waitcnt vmcnt(0)" ::: "memory");
  __builtin_amdgcn_s_barrier();

#pragma unroll 1
  for (int kt = 0; kt < NKT; ++kt) {
    const unsigned short* Ab = As[kt & 1];
    const unsigned short* Bb = Bs[kt & 1];
    unsigned short* An = (unsigned short*)As[(kt & 1) ^ 1];
    unsigned short* Bn = (unsigned short*)Bs[(kt & 1) ^ 1];
    bool pf = (kt + 1 < NKT);

    short8 bfrag[4];
#pragma unroll
    for (int p = 0; p < 4; ++p) {                    // phase: kk = p>>1, A-half = p&1
      const int kk = p >> 1, ah = p & 1;
      const int koff = kk ? koff1 : koff0;
      short8 afrag[4];
      if (ah == 0) {
#pragma unroll
        for (int ni = 0; ni < 4; ni++)
          bfrag[ni] = *(const short8*)&Bb[bbase + ni * 1024 + koff];
      }
#pragma unroll
      for (int m = 0; m < 4; m++)
        afrag[m] = *(const short8*)&Ab[abase + (ah * 4 + m) * 1024 + koff];

      if (pf) {                                      // 2 of 8 next-tile loads/phase
        if (p < 2) {
          gl_lds16(gsrcA[2 * p],     An + (2 * p) * 4096 + ldst);
          gl_lds16(gsrcA[2 * p + 1], An + (2 * p + 1) * 4096 + ldst);
          gsrcA[2 * p] += 64; gsrcA[2 * p + 1] += 64;
        } else {
          const int q = 2 * (p - 2);
          gl_lds16(gsrcB[q],     Bn + q * 4096 + ldst);
          gl_lds16(gsrcB[q + 1], Bn + (q + 1) * 4096 + ldst);
          gsrcB[q] += 64; gsrcB[q + 1] += 64;
        }
      }

      __builtin_amdgcn_s_barrier();
      asm volatile("s_waitcnt lgkmcnt(0)" ::: "memory");
      __builtin_amdgcn_sched_barrier(0);
      __builtin_amdgcn_s_setprio(1);
#pragma unroll
      for (int ni = 0; ni < 4; ni++)
#pragma unroll
        for (int m = 0; m < 4; m++)
          acc[ah * 4 + m][ni] = __builtin_amdgcn_mfma_f32_16x16x32_bf16(
              afrag[m], bfrag[ni], acc[ah * 4 + m][ni], 0, 0, 0);
      __builtin_amdgcn_s_setprio(0);
      __builtin_amdgcn_sched_barrier(0);
      if (p == 3 && pf)
        asm volatile("s_waitcnt vmcnt(0)" ::: "memory");  // once per K-tile
      __builtin_amdgcn_s_barrier();
    }
  }

#pragma unroll
  for (int ni = 0; ni < 4; ni++) {
    int n = j0 + wc * 64 + ni * 16 + l15;
    float bv = bias[t * N + n];
#pragma unroll
    for (int m = 0; m < 8; m++) {
      int mb = wr * 128 + m * 16 + quad * 4;
#pragma unroll
      for (int r = 0; r < 4; r++) {
        int tok = toks[mb + r];
        if (tok >= 0) {
          float v = acc[m][ni][r] + bv;
          if (GELU) {
            v = 0.5f * v * (1.f + erff(v * 0.70710678118654752f));
            Hout[(size_t)tok * N + n] = f2bf(v);
          } else {
            Fout[(size_t)tok * N + n] = v;
          }
        }
      }
    }
  }
}

// ====== gemm2: 3-buffer pipeline, counted vmcnt(4), XCD-pinned (R4 proven) ===
template<int K, int N, int NXB, bool GELU>
__global__ __launch_bounds__(256) void gemm_pipe_kernel(
    const unsigned short* __restrict__ A, const unsigned short* __restrict__ BT,
    const float* __restrict__ bias, const int* __restrict__ counts,
    const int* __restrict__ list, unsigned short* __restrict__ Hout,
    float* __restrict__ Fout) {
  unsigned bid = blockIdx.x;
  int t = bid & (NT - 1);
  unsigned inner = bid >> 3;
  int bx = inner & (NXB - 1);
  int by = inner / NXB;

  int count = counts[t];
  int base = by * BM;
  if (base >= count) return;
  int j0 = bx * BN;

  __shared__ __align__(16) unsigned short As[3][BM * BK];   // 3 x 8 KB
  __shared__ __align__(16) unsigned short Bs[3][BN * BK];   // 3 x 8 KB
  __shared__ int toks[BM];

  int tid = threadIdx.x;
  if (tid < BM) {
    int slot = base + tid;
    toks[tid] = (slot < count) ? list[t * NTOK + slot] : -1;
  }
  __syncthreads();

  int w = tid >> 6, lane = tid & 63;
  int lrow = lane >> 2;
  int lc   = lane & 3;
  int swz  = (lc ^ ((lrow >> 1) & 3)) * 8;

  const unsigned short* srcA[2];
  const unsigned short* srcB[2];
  int cho[2];
#pragma unroll
  for (int i = 0; i < 2; i++) {
    int ch = i * 4 + w;
    int r = ch * 16 + lrow;
    int tk = toks[r]; if (tk < 0) tk = 0;
    srcA[i] = A + (size_t)tk * K + swz;
    srcB[i] = BT + (size_t)t * N * K + (size_t)(j0 + r) * K + swz;
    cho[i] = ch * 512;
  }

  int wm = (w & 1) * 64, wn = (w >> 1) * 64;
  int quad = lane >> 4, l15 = lane & 15;
  int fswz = (quad ^ ((l15 >> 1) & 3)) * 8;

  floatx4 acc[4][4];
#pragma unroll
  for (int mi = 0; mi < 4; mi++)
#pragma unroll
    for (int ni = 0; ni < 4; ni++) acc[mi][ni] = (floatx4){0.f, 0.f, 0.f, 0.f};

  constexpr int S = K / BK;
  unsigned short *a0 = As[0], *a1 = As[1], *a2 = As[2];
  unsigned short *b0 = Bs[0], *b1 = Bs[1], *b2 = Bs[2];

#pragma unroll
  for (int i = 0; i < 2; i++) {
    gl_lds16(srcA[i], a0 + cho[i]); gl_lds16(srcB[i], b0 + cho[i]);
    srcA[i] += BK; srcB[i] += BK;
  }
#pragma unroll
  for (int i = 0; i < 2; i++) {
    gl_lds16(srcA[i], a1 + cho[i]); gl_lds16(srcB[i], b1 + cho[i]);
    srcA[i] += BK; srcB[i] += BK;
  }
  asm volatile("s_waitcnt vmcnt(4)" ::: "memory");
  __builtin_amdgcn_s_barrier();

#pragma unroll 1
  for (int k = 0; k < S - 1; ++k) {
    short8 a[4], b[4];
#pragma unroll
    for (int mi = 0; mi < 4; mi++)
      a[mi] = *(const short8*)&a0[(wm + mi * 16 + l15) * BK + fswz];
#pragma unroll
    for (int ni = 0; ni < 4; ni++)
      b[ni] = *(const short8*)&b0[(wn + ni * 16 + l15) * BK + fswz];

    if (k < S - 2) {
#pragma unroll
      for (int i = 0; i < 2; i++) {
        gl_lds16(srcA[i], a2 + cho[i]); gl_lds16(srcB[i], b2 + cho[i]);
        srcA[i] += BK; srcB[i] += BK;
      }
    }

    __builtin_amdgcn_s_setprio(1);
#pragma unroll
    for (int mi = 0; mi < 4; mi++)
#pragma unroll
      for (int ni = 0; ni < 4; ni++)
        acc[mi][ni] = __builtin_amdgcn_mfma_f32_16x16x32_bf16(a[mi], b[ni], acc[mi][ni], 0, 0, 0);
    __builtin_amdgcn_s_setprio(0);

    if (k < S - 2) {
      asm volatile("s_waitcnt vmcnt(4)" ::: "memory");
    } else {
      asm volatile("s_waitcnt vmcnt(0)" ::: "memory");
    }
    __builtin_amdgcn_s_barrier();

    unsigned short* tp;
    tp = a0; a0 = a1; a1 = a2; a2 = tp;
    tp = b0; b0 = b1; b1 = b2; b2 = tp;
  }

  {
    short8 a[4], b[4];
#pragma unroll
    for (int mi = 0; mi < 4; mi++)
      a[mi] = *(const short8*)&a0[(wm + mi * 16 + l15) * BK + fswz];
#pragma unroll
    for (int ni = 0; ni < 4; ni++)
      b[ni] = *(const short8*)&b0[(wn + ni * 16 + l15) * BK + fswz];
#pragma unroll
    for (int mi = 0; mi < 4; mi++)
#pragma unroll
      for (int ni = 0; ni < 4; ni++)
        acc[mi][ni] = __builtin_amdgcn_mfma_f32_16x16x32_bf16(a[mi], b[ni], acc[mi][ni], 0, 0, 0);
  }

#pragma unroll
  for (int ni = 0; ni < 4; ni++) {
    int n = j0 + wn + ni * 16 + l15;
    float bv = bias[t * N + n];
#pragma unroll
    for (int mi = 0; mi < 4; mi++) {
      int mb = wm + mi * 16 + quad * 4;
#pragma unroll
      for (int r = 0; r < 4; r++) {
        int tok = toks[mb + r];
        if (tok >= 0) {
          float v = acc[mi][ni][r] + bv;
          if (GELU) {
            v = 0.5f * v * (1.f + erff(v * 0.70710678118654752f));
            Hout[(size_t)tok * N + n] = f2bf(v);
          } else {
            Fout[(size_t)tok * N + n] = v;
          }
        }
      }
    }
  }
}

// ================= fallback (round-1 kernels, used if ws too small) ==========
#define KPAD 40
__global__ __launch_bounds__(256) void gemm1_fb(
    const unsigned short* __restrict__ xb, const float* __restrict__ W1,
    const float* __restrict__ b1, const int* __restrict__ counts,
    const int* __restrict__ list, unsigned short* __restrict__ H) {
  int t = blockIdx.z;
  int count = counts[t];
  int base = blockIdx.y * BM;
  if (base >= count) return;
  int j0 = blockIdx.x * BN;
  __shared__ unsigned short As[BM][KPAD];
  __shared__ unsigned short Bs[BN][KPAD];
  __shared__ int toks[BM];
  int tid = threadIdx.x;
  if (tid < BM) {
    int slot = base + tid;
    toks[tid] = (slot < count) ? list[t * NTOK + slot] : -1;
  }
  __syncthreads();
  int arow = tid >> 1, acol = (tid & 1) * 16;
  int mytok = toks[arow];
  const unsigned short* xrow = xb + (size_t)(mytok < 0 ? 0 : mytok) * DC;
  int kg4 = (tid >> 5) * 4, ng4 = (tid & 31) * 4;
  const float* Wt = W1 + (size_t)t * DC * DH;
  int wid = tid >> 6, lane = tid & 63;
  int wm = (wid & 1) * 64, wn = (wid >> 1) * 64;
  int quad = lane >> 4, l15 = lane & 15;
  floatx4 acc[4][4];
#pragma unroll
  for (int mi = 0; mi < 4; mi++)
#pragma unroll
    for (int ni = 0; ni < 4; ni++) acc[mi][ni] = (floatx4){0.f, 0.f, 0.f, 0.f};
  for (int kt = 0; kt < DC / BK; kt++) {
    int k0 = kt * BK;
    if (mytok >= 0) {
      *(uint4*)&As[arow][acol]     = *(const uint4*)(xrow + k0 + acol);
      *(uint4*)&As[arow][acol + 8] = *(const uint4*)(xrow + k0 + acol + 8);
    } else {
      uint4 z = {0u,0u,0u,0u};
      *(uint4*)&As[arow][acol] = z; *(uint4*)&As[arow][acol + 8] = z;
    }
    const float* wb = Wt + (size_t)(k0 + kg4) * DH + j0 + ng4;
    float4 r0 = *(const float4*)(wb);
    float4 r1 = *(const float4*)(wb + DH);
    float4 r2 = *(const float4*)(wb + 2 * DH);
    float4 r3 = *(const float4*)(wb + 3 * DH);
    ushort4v c0 = { f2bf(r0.x), f2bf(r1.x), f2bf(r2.x), f2bf(r3.x) };
    ushort4v c1 = { f2bf(r0.y), f2bf(r1.y), f2bf(r2.y), f2bf(r3.y) };
    ushort4v c2 = { f2bf(r0.z), f2bf(r1.z), f2bf(r2.z), f2bf(r3.z) };
    ushort4v c3 = { f2bf(r0.w), f2bf(r1.w), f2bf(r2.w), f2bf(r3.w) };
    *(ushort4v*)&Bs[ng4 + 0][kg4] = c0; *(ushort4v*)&Bs[ng4 + 1][kg4] = c1;
    *(ushort4v*)&Bs[ng4 + 2][kg4] = c2; *(ushort4v*)&Bs[ng4 + 3][kg4] = c3;
    __syncthreads();
    short8 a[4], b[4];
#pragma unroll
    for (int mi = 0; mi < 4; mi++) a[mi] = *(const short8*)&As[wm + mi * 16 + l15][quad * 8];
#pragma unroll
    for (int ni = 0; ni < 4; ni++) b[ni] = *(const short8*)&Bs[wn + ni * 16 + l15][quad * 8];
#pragma unroll
    for (int mi = 0; mi < 4; mi++)
#pragma unroll
      for (int ni = 0; ni < 4; ni++)
        acc[mi][ni] = __builtin_amdgcn_mfma_f32_16x16x32_bf16(a[mi], b[ni], acc[mi][ni], 0, 0, 0);
    __syncthreads();
  }
#pragma unroll
  for (int ni = 0; ni < 4; ni++) {
    int n = j0 + wn + ni * 16 + l15;
    float bias = b1[t * DH + n];
#pragma unroll
    for (int mi = 0; mi < 4; mi++) {
      int mb = wm + mi * 16 + quad * 4;
#pragma unroll
      for (int r = 0; r < 4; r++) {
        int tok = toks[mb + r];
        if (tok >= 0) {
          float v = acc[mi][ni][r] + bias;
          v = 0.5f * v * (1.f + erff(v * 0.70710678118654752f));
          H[(size_t)tok * DH + n] = f2bf(v);
        }
      }
    }
  }
}

__global__ __launch_bounds__(256) void gemm2_fb(
    const unsigned short* __restrict__ H, const float* __restrict__ W2,
    const float* __restrict__ b2, const int* __restrict__ counts,
    const int* __restrict__ list, float* __restrict__ out) {
  int t = blockIdx.z;
  int count = counts[t];
  int base = blockIdx.y * BM;
  if (base >= count) return;
  int j0 = blockIdx.x * BN;
  __shared__ unsigned short As[BM][KPAD];
  __shared__ unsigned short Bs[BN][KPAD];
  __shared__ int toks[BM];
  int tid = threadIdx.x;
  if (tid < BM) {
    int slot = base + tid;
    toks[tid] = (slot < count) ? list[t * NTOK + slot] : -1;
  }
  __syncthreads();
  int arow = tid >> 1, acol = (tid & 1) * 16;
  int mytok = toks[arow];
  const unsigned short* hrow = H + (size_t)(mytok < 0 ? 0 : mytok) * DH;
  int kg4 = (tid >> 5) * 4, ng4 = (tid & 31) * 4;
  const float* Wt = W2 + (size_t)t * DH * DC;
  int wid = tid >> 6, lane = tid & 63;
  int wm = (wid & 1) * 64, wn = (wid >> 1) * 64;
  int quad = lane >> 4, l15 = lane & 15;
  floatx4 acc[4][4];
#pragma unroll
  for (int mi = 0; mi < 4; mi++)
#pragma unroll
    for (int ni = 0; ni < 4; ni++) acc[mi][ni] = (floatx4){0.f, 0.f, 0.f, 0.f};
  for (int kt = 0; kt < DH / BK; kt++) {
    int k0 = kt * BK;
    if (mytok >= 0) {
      *(uint4*)&As[arow][acol]     = *(const uint4*)(hrow + k0 + acol);
      *(uint4*)&As[arow][acol + 8] = *(const uint4*)(hrow + k0 + acol + 8);
    } else {
      uint4 z = {0u,0u,0u,0u};
      *(uint4*)&As[arow][acol] = z; *(uint4*)&As[arow][acol + 8] = z;
    }
    const float* wb = Wt + (size_t)(k0 + kg4) * DC + j0 + ng4;
    float4 r0 = *(const float4*)(wb);
    float4 r1 = *(const float4*)(wb + DC);
    float4 r2 = *(const float4*)(wb + 2 * DC);
    float4 r3 = *(const float4*)(wb + 3 * DC);
    ushort4v c0 = { f2bf(r0.x), f2bf(r1.x), f2bf(r2.x), f2bf(r3.x) };
    ushort4v c1 = { f2bf(r0.y), f2bf(r1.y), f2bf(r2.y), f2bf(r3.y) };
    ushort4v c2 = { f2bf(r0.z), f2bf(r1.z), f2bf(r2.z), f2bf(r3.z) };
    ushort4v c3 = { f2bf(r0.w), f2bf(r1.w), f2bf(r2.w), f2bf(r3.w) };
    *(ushort4v*)&Bs[ng4 + 0][kg4] = c0; *(ushort4v*)&Bs[ng4 + 1][kg4] = c1;
    *(ushort4v*)&Bs[ng4 + 2][kg4] = c2; *(ushort4v*)&Bs[ng4 + 3][kg4] = c3;
    __syncthreads();
    short8 a[4], b[4];
#pragma unroll
    for (int mi = 0; mi < 4; mi++) a[mi] = *(const short8*)&As[wm + mi * 16 + l15][quad * 8];
#pragma unroll
    for (int ni = 0; ni < 4; ni++) b[ni] = *(const short8*)&Bs[wn + ni * 16 + l15][quad * 8];
#pragma unroll
    for (int mi = 0; mi < 4; mi++)
#pragma unroll
      for (int ni = 0; ni < 4; ni++)
        acc[mi][ni] = __builtin_amdgcn_mfma_f32_16x16x32_bf16(a[mi], b[ni], acc[mi][ni], 0, 0, 0);
    __syncthreads();
  }
#pragma unroll
  for (int ni = 0; ni < 4; ni++) {
    int n = j0 + wn + ni * 16 + l15;
    float bias = b2[t * DC + n];
#pragma unroll
    for (int mi = 0; mi < 4; mi++) {
      int mb = wm + mi * 16 + quad * 4;
#pragma unroll
      for (int r = 0; r < 4; r++) {
        int tok = toks[mb + r];
        if (tok >= 0) out[(size_t)tok * DC + n] = acc[mi][ni][r] + bias;
      }
    }
  }
}

extern "C" void kernel_launch(void* const* d_in, const int* in_sizes, int n_in,
                              void* d_out, int out_size, void* d_ws, size_t ws_size,
                              hipStream_t stream) {
  const float* x        = (const float*)d_in[0];
  const float* pe       = (const float*)d_in[1];
  const float* pwp      = (const float*)d_in[2];
  const float* cwp      = (const float*)d_in[3];
  const float* pos_sigs = (const float*)d_in[4];
  const float* csigs    = (const float*)d_in[5];
  const float* W1       = (const float*)d_in[6];
  const float* b1       = (const float*)d_in[7];
  const float* W2       = (const float*)d_in[8];
  const float* b2       = (const float*)d_in[9];
  float* out = (float*)d_out;

  char* ws = (char*)d_ws;
  int* counts = (int*)ws;                       // 32 B
  int* list   = (int*)(ws + 1024);              // 256 KB
  unsigned short* xb = (unsigned short*)(ws + (1 << 20));  // 16 MB @ [1,17)

  hipMemsetAsync(counts, 0, NT * sizeof(int), stream);
  route_kernel<<<NTOK / 4, 256, 0, stream>>>(x, pe, pwp, cwp, pos_sigs, csigs,
                                             counts, list, xb);

  if (ws_size >= (size_t)145 * 1024 * 1024) {
    // fast path: WT @ [17,81) (reused for W1T then W2T), H @ [81,145)
    unsigned short* WT = (unsigned short*)(ws + ((size_t)17 << 20));
    unsigned short* H  = (unsigned short*)(ws + ((size_t)81 << 20));

    transpose_kernel<DC, DH><<<dim3(DH / 64, DC / 64, NT), 256, 0, stream>>>(W1, WT);
    // gemm1: 256x256 8-wave 4-phase schedule, unpinned 3D grid
    gemm8p_kernel<DC, DH, true><<<dim3(DH / 256, NTOK / 256, NT), 512, 0, stream>>>(
        xb, WT, b1, counts, list, H, nullptr);
    transpose_kernel<DH, DC><<<dim3(DC / 64, DH / 64, NT), 256, 0, stream>>>(W2, WT);
    // gemm2: XCD-pinned 3-buffer pipe (R4 proven)
    gemm_pipe_kernel<DH, DC, DC / BN, false>
        <<<(DC / BN) * (NTOK / BM) * NT, 256, 0, stream>>>(
        H, WT, b2, counts, list, nullptr, out);
  } else {
    // fallback: round-1 structure, 96 MB footprint
    unsigned short* H = (unsigned short*)(ws + ((size_t)32 << 20));
    gemm1_fb<<<dim3(DH / BN, NTOK / BM, NT), 256, 0, stream>>>(xb, W1, b1, counts, list, H);
    gemm2_fb<<<dim3(DC / BN, NTOK / BM, NT), 256, 0, stream>>>(H, W2, b2, counts, list, out);
  }
}

// Round 6
// 597.828 us; speedup vs baseline: 1.2234x; 1.2234x over previous
//
#include <hip/hip_runtime.h>
#include <hip/hip_bf16.h>
#include <math.h>

#define BATCH 16
#define SEQ   512
#define DC    1024
#define DP    64
#define NT    8
#define DH    4096
#define NTOK  (BATCH*SEQ)   // 8192

#define BM 128
#define BN 128
#define BK 32

typedef __attribute__((ext_vector_type(8))) short short8;        // 8 bf16
typedef __attribute__((ext_vector_type(4))) float floatx4;       // MFMA acc
typedef __attribute__((ext_vector_type(4))) unsigned short ushort4v;
typedef __attribute__((ext_vector_type(8))) unsigned short ushort8v;

__device__ __forceinline__ unsigned short f2bf(float f) {
  union { float f; unsigned u; } v; v.f = f;
  unsigned r = v.u + 0x7FFFu + ((v.u >> 16) & 1u);   // round-to-nearest-even
  return (unsigned short)(r >> 16);
}

// async global -> LDS, 16B per lane, LDS dst = uniform base + lane*16
__device__ __forceinline__ void gl_lds16(const void* g, void* l) {
  __builtin_amdgcn_global_load_lds(
      (__attribute__((address_space(1))) void*)g,
      (__attribute__((address_space(3))) void*)l, 16, 0, 0);
}

// ---------- routing pass 1: score + argmax per token, write best[] ----------
// (also writes bf16 copy of x). NO atomics: R0-R5 ended with 8192 waves doing
// atomicAdd into ONE 64B line (counts[0..7]) -> cross-XCD line ping-pong,
// suspected ~100-300us serialization tail (the constant ~394us non-gemm time).
__global__ __launch_bounds__(256) void route_score(
    const float* __restrict__ x, const float* __restrict__ pe,
    const float* __restrict__ pwp, const float* __restrict__ cwp,
    const float* __restrict__ pos_sigs, const float* __restrict__ csigs,
    int* __restrict__ best, unsigned short* __restrict__ xb) {
  int wid  = threadIdx.x >> 6;
  int lane = threadIdx.x & 63;
  int token = blockIdx.x * 4 + wid;
  int s = token & (SEQ - 1);

  float pwr = 1.f / (1.f + expf(-pwp[0]));
  float cwr = 1.f / (1.f + expf(-cwp[0]));
  float tot = pwr + cwr;
  float pw = pwr / tot, cw = cwr / tot;

  float acc[NT];
#pragma unroll
  for (int t = 0; t < NT; t++) acc[t] = 0.f;

  float a0 = pw * pe[s * DP + lane];
#pragma unroll
  for (int t = 0; t < NT; t++) {
    float v = pos_sigs[t * DP + lane];
    float sg = (v > 0.f) ? 1.f : ((v < 0.f) ? -1.f : 0.f);
    acc[t] = fmaf(a0, sg, acc[t]);
  }

  const float* xrow = x + (size_t)token * DC;
  unsigned short* xbrow = xb + (size_t)token * DC;
#pragma unroll 4
  for (int i = 0; i < DC / 64; i++) {
    int c = lane + i * 64;
    float xv = xrow[c];
    xbrow[c] = f2bf(xv);
    float a = cw * xv;
#pragma unroll
    for (int t = 0; t < NT; t++) {
      float v = csigs[t * DC + c];
      float sg = (v > 0.f) ? 1.f : ((v < 0.f) ? -1.f : 0.f);
      acc[t] = fmaf(a, sg, acc[t]);
    }
  }

#pragma unroll
  for (int off = 32; off >= 1; off >>= 1)
#pragma unroll
    for (int t = 0; t < NT; t++) acc[t] += __shfl_xor(acc[t], off);

  if (lane == 0) {
    int bt = 0; float bv = acc[0];
#pragma unroll
    for (int t = 1; t < NT; t++)
      if (acc[t] > bv) { bv = acc[t]; bt = t; }
    best[token] = bt;
  }
}

// ---------- routing pass 2: stable compaction, one block per tile ----------
// Block t scans best[0..NTOK), ballot+popc prefix-scan -> list entries in
// token order, counts[t] written once at the end. Zero atomics.
__global__ __launch_bounds__(256) void route_compact(
    const int* __restrict__ best, int* __restrict__ counts,
    int* __restrict__ list) {
  int t = blockIdx.x;
  int tid = threadIdx.x;
  int lane = tid & 63, wid = tid >> 6;
  __shared__ int wsum[4];
  int running = 0;
  for (int base = 0; base < NTOK; base += 256) {
    int tok = base + tid;
    bool f = (best[tok] == t);
    unsigned long long m = __ballot(f);
    int rank = __popcll(m & ((1ULL << lane) - 1ULL));
    if (lane == 0) wsum[wid] = __popcll(m);
    __syncthreads();
    int wb = 0;
#pragma unroll
    for (int i = 0; i < 4; i++) if (i < wid) wb += wsum[i];
    int ctot = wsum[0] + wsum[1] + wsum[2] + wsum[3];
    if (f) list[t * NTOK + running + wb + rank] = tok;
    running += ctot;
    __syncthreads();
  }
  if (tid == 0) counts[t] = running;
}

// ------------- transpose+convert: in [AR][AC] fp32 -> out [AC][AR] bf16 ------
template<int AR, int AC>
__global__ __launch_bounds__(256) void transpose_kernel(
    const float* __restrict__ in, unsigned short* __restrict__ out) {
  __shared__ unsigned short tile[64 * 65];
  int t = blockIdx.z;
  const float* in_t = in + (size_t)t * AR * AC;
  unsigned short* out_t = out + (size_t)t * AR * AC;
  int x0 = blockIdx.x * 64, y0 = blockIdx.y * 64;
  int tid = threadIdx.x;
  int ry = tid >> 2, cx = (tid & 3) * 16;
  const float* src = in_t + (size_t)(y0 + ry) * AC + x0 + cx;
  float4 v0 = *(const float4*)(src);
  float4 v1 = *(const float4*)(src + 4);
  float4 v2 = *(const float4*)(src + 8);
  float4 v3 = *(const float4*)(src + 12);
  unsigned short* trow = &tile[ry * 65 + cx];
  trow[0]  = f2bf(v0.x); trow[1]  = f2bf(v0.y); trow[2]  = f2bf(v0.z); trow[3]  = f2bf(v0.w);
  trow[4]  = f2bf(v1.x); trow[5]  = f2bf(v1.y); trow[6]  = f2bf(v1.z); trow[7]  = f2bf(v1.w);
  trow[8]  = f2bf(v2.x); trow[9]  = f2bf(v2.y); trow[10] = f2bf(v2.z); trow[11] = f2bf(v2.w);
  trow[12] = f2bf(v3.x); trow[13] = f2bf(v3.y); trow[14] = f2bf(v3.z); trow[15] = f2bf(v3.w);
  __syncthreads();
  int rx = tid >> 2, cy = (tid & 3) * 16;
  ushort8v o0, o1;
#pragma unroll
  for (int j = 0; j < 8; j++) o0[j] = tile[(cy + j) * 65 + rx];
#pragma unroll
  for (int j = 0; j < 8; j++) o1[j] = tile[(cy + 8 + j) * 65 + rx];
  size_t ob = (size_t)(x0 + rx) * AR + y0 + cy;
  *(ushort8v*)&out_t[ob]     = o0;
  *(ushort8v*)&out_t[ob + 8] = o1;
}

// ====== gemm1: 3-buffer pipeline, counted vmcnt(4), UNPINNED 3D grid =========
// (R3 measured 153us; R4 pinning regressed it to 192 -- gemm1's FETCH was
// already ideal, pinning only added per-tile load imbalance.)
template<int K, int N, bool GELU>
__global__ __launch_bounds__(256) void gemm_pipe3d_kernel(
    const unsigned short* __restrict__ A, const unsigned short* __restrict__ BT,
    const float* __restrict__ bias, const int* __restrict__ counts,
    const int* __restrict__ list, unsigned short* __restrict__ Hout,
    float* __restrict__ Fout) {
  int t = blockIdx.z;
  int count = counts[t];
  int base = blockIdx.y * BM;
  if (base >= count) return;
  int j0 = blockIdx.x * BN;

  __shared__ __align__(16) unsigned short As[3][BM * BK];   // 3 x 8 KB
  __shared__ __align__(16) unsigned short Bs[3][BN * BK];   // 3 x 8 KB
  __shared__ int toks[BM];

  int tid = threadIdx.x;
  if (tid < BM) {
    int slot = base + tid;
    toks[tid] = (slot < count) ? list[t * NTOK + slot] : -1;
  }
  __syncthreads();

  int w = tid >> 6, lane = tid & 63;
  int lrow = lane >> 2;
  int lc   = lane & 3;
  int swz  = (lc ^ ((lrow >> 1) & 3)) * 8;

  const unsigned short* srcA[2];
  const unsigned short* srcB[2];
  int cho[2];
#pragma unroll
  for (int i = 0; i < 2; i++) {
    int ch = i * 4 + w;
    int r = ch * 16 + lrow;
    int tk = toks[r]; if (tk < 0) tk = 0;
    srcA[i] = A + (size_t)tk * K + swz;
    srcB[i] = BT + (size_t)t * N * K + (size_t)(j0 + r) * K + swz;
    cho[i] = ch * 512;
  }

  int wm = (w & 1) * 64, wn = (w >> 1) * 64;
  int quad = lane >> 4, l15 = lane & 15;
  int fswz = (quad ^ ((l15 >> 1) & 3)) * 8;

  floatx4 acc[4][4];
#pragma unroll
  for (int mi = 0; mi < 4; mi++)
#pragma unroll
    for (int ni = 0; ni < 4; ni++) acc[mi][ni] = (floatx4){0.f, 0.f, 0.f, 0.f};

  constexpr int S = K / BK;
  unsigned short *a0 = As[0], *a1 = As[1], *a2 = As[2];
  unsigned short *b0 = Bs[0], *b1 = Bs[1], *b2 = Bs[2];

#pragma unroll
  for (int i = 0; i < 2; i++) {
    gl_lds16(srcA[i], a0 + cho[i]); gl_lds16(srcB[i], b0 + cho[i]);
    srcA[i] += BK; srcB[i] += BK;
  }
#pragma unroll
  for (int i = 0; i < 2; i++) {
    gl_lds16(srcA[i], a1 + cho[i]); gl_lds16(srcB[i], b1 + cho[i]);
    srcA[i] += BK; srcB[i] += BK;
  }
  asm volatile("s_waitcnt vmcnt(4)" ::: "memory");
  __builtin_amdgcn_s_barrier();

#pragma unroll 1
  for (int k = 0; k < S - 1; ++k) {
    short8 a[4], b[4];
#pragma unroll
    for (int mi = 0; mi < 4; mi++)
      a[mi] = *(const short8*)&a0[(wm + mi * 16 + l15) * BK + fswz];
#pragma unroll
    for (int ni = 0; ni < 4; ni++)
      b[ni] = *(const short8*)&b0[(wn + ni * 16 + l15) * BK + fswz];

    if (k < S - 2) {
#pragma unroll
      for (int i = 0; i < 2; i++) {
        gl_lds16(srcA[i], a2 + cho[i]); gl_lds16(srcB[i], b2 + cho[i]);
        srcA[i] += BK; srcB[i] += BK;
      }
    }

    __builtin_amdgcn_s_setprio(1);
#pragma unroll
    for (int mi = 0; mi < 4; mi++)
#pragma unroll
      for (int ni = 0; ni < 4; ni++)
        acc[mi][ni] = __builtin_amdgcn_mfma_f32_16x16x32_bf16(a[mi], b[ni], acc[mi][ni], 0, 0, 0);
    __builtin_amdgcn_s_setprio(0);

    if (k < S - 2) {
      asm volatile("s_waitcnt vmcnt(4)" ::: "memory");
    } else {
      asm volatile("s_waitcnt vmcnt(0)" ::: "memory");
    }
    __builtin_amdgcn_s_barrier();

    unsigned short* tp;
    tp = a0; a0 = a1; a1 = a2; a2 = tp;
    tp = b0; b0 = b1; b1 = b2; b2 = tp;
  }

  {
    short8 a[4], b[4];
#pragma unroll
    for (int mi = 0; mi < 4; mi++)
      a[mi] = *(const short8*)&a0[(wm + mi * 16 + l15) * BK + fswz];
#pragma unroll
    for (int ni = 0; ni < 4; ni++)
      b[ni] = *(const short8*)&b0[(wn + ni * 16 + l15) * BK + fswz];
#pragma unroll
    for (int mi = 0; mi < 4; mi++)
#pragma unroll
      for (int ni = 0; ni < 4; ni++)
        acc[mi][ni] = __builtin_amdgcn_mfma_f32_16x16x32_bf16(a[mi], b[ni], acc[mi][ni], 0, 0, 0);
  }

#pragma unroll
  for (int ni = 0; ni < 4; ni++) {
    int n = j0 + wn + ni * 16 + l15;
    float bv = bias[t * N + n];
#pragma unroll
    for (int mi = 0; mi < 4; mi++) {
      int mb = wm + mi * 16 + quad * 4;
#pragma unroll
      for (int r = 0; r < 4; r++) {
        int tok = toks[mb + r];
        if (tok >= 0) {
          float v = acc[mi][ni][r] + bv;
          if (GELU) {
            v = 0.5f * v * (1.f + erff(v * 0.70710678118654752f));
            Hout[(size_t)tok * N + n] = f2bf(v);
          } else {
            Fout[(size_t)tok * N + n] = v;
          }
        }
      }
    }
  }
}

// ====== gemm2: 3-buffer pipeline, counted vmcnt(4), XCD-pinned (R4: ~113us) ==
template<int K, int N, int NXB, bool GELU>
__global__ __launch_bounds__(256) void gemm_pipe_kernel(
    const unsigned short* __restrict__ A, const unsigned short* __restrict__ BT,
    const float* __restrict__ bias, const int* __restrict__ counts,
    const int* __restrict__ list, unsigned short* __restrict__ Hout,
    float* __restrict__ Fout) {
  unsigned bid = blockIdx.x;
  int t = bid & (NT - 1);
  unsigned inner = bid >> 3;
  int bx = inner & (NXB - 1);
  int by = inner / NXB;

  int count = counts[t];
  int base = by * BM;
  if (base >= count) return;
  int j0 = bx * BN;

  __shared__ __align__(16) unsigned short As[3][BM * BK];   // 3 x 8 KB
  __shared__ __align__(16) unsigned short Bs[3][BN * BK];   // 3 x 8 KB
  __shared__ int toks[BM];

  int tid = threadIdx.x;
  if (tid < BM) {
    int slot = base + tid;
    toks[tid] = (slot < count) ? list[t * NTOK + slot] : -1;
  }
  __syncthreads();

  int w = tid >> 6, lane = tid & 63;
  int lrow = lane >> 2;
  int lc   = lane & 3;
  int swz  = (lc ^ ((lrow >> 1) & 3)) * 8;

  const unsigned short* srcA[2];
  const unsigned short* srcB[2];
  int cho[2];
#pragma unroll
  for (int i = 0; i < 2; i++) {
    int ch = i * 4 + w;
    int r = ch * 16 + lrow;
    int tk = toks[r]; if (tk < 0) tk = 0;
    srcA[i] = A + (size_t)tk * K + swz;
    srcB[i] = BT + (size_t)t * N * K + (size_t)(j0 + r) * K + swz;
    cho[i] = ch * 512;
  }

  int wm = (w & 1) * 64, wn = (w >> 1) * 64;
  int quad = lane >> 4, l15 = lane & 15;
  int fswz = (quad ^ ((l15 >> 1) & 3)) * 8;

  floatx4 acc[4][4];
#pragma unroll
  for (int mi = 0; mi < 4; mi++)
#pragma unroll
    for (int ni = 0; ni < 4; ni++) acc[mi][ni] = (floatx4){0.f, 0.f, 0.f, 0.f};

  constexpr int S = K / BK;
  unsigned short *a0 = As[0], *a1 = As[1], *a2 = As[2];
  unsigned short *b0 = Bs[0], *b1 = Bs[1], *b2 = Bs[2];

#pragma unroll
  for (int i = 0; i < 2; i++) {
    gl_lds16(srcA[i], a0 + cho[i]); gl_lds16(srcB[i], b0 + cho[i]);
    srcA[i] += BK; srcB[i] += BK;
  }
#pragma unroll
  for (int i = 0; i < 2; i++) {
    gl_lds16(srcA[i], a1 + cho[i]); gl_lds16(srcB[i], b1 + cho[i]);
    srcA[i] += BK; srcB[i] += BK;
  }
  asm volatile("s_waitcnt vmcnt(4)" ::: "memory");
  __builtin_amdgcn_s_barrier();

#pragma unroll 1
  for (int k = 0; k < S - 1; ++k) {
    short8 a[4], b[4];
#pragma unroll
    for (int mi = 0; mi < 4; mi++)
      a[mi] = *(const short8*)&a0[(wm + mi * 16 + l15) * BK + fswz];
#pragma unroll
    for (int ni = 0; ni < 4; ni++)
      b[ni] = *(const short8*)&b0[(wn + ni * 16 + l15) * BK + fswz];

    if (k < S - 2) {
#pragma unroll
      for (int i = 0; i < 2; i++) {
        gl_lds16(srcA[i], a2 + cho[i]); gl_lds16(srcB[i], b2 + cho[i]);
        srcA[i] += BK; srcB[i] += BK;
      }
    }

    __builtin_amdgcn_s_setprio(1);
#pragma unroll
    for (int mi = 0; mi < 4; mi++)
#pragma unroll
      for (int ni = 0; ni < 4; ni++)
        acc[mi][ni] = __builtin_amdgcn_mfma_f32_16x16x32_bf16(a[mi], b[ni], acc[mi][ni], 0, 0, 0);
    __builtin_amdgcn_s_setprio(0);

    if (k < S - 2) {
      asm volatile("s_waitcnt vmcnt(4)" ::: "memory");
    } else {
      asm volatile("s_waitcnt vmcnt(0)" ::: "memory");
    }
    __builtin_amdgcn_s_barrier();

    unsigned short* tp;
    tp = a0; a0 = a1; a1 = a2; a2 = tp;
    tp = b0; b0 = b1; b1 = b2; b2 = tp;
  }

  {
    short8 a[4], b[4];
#pragma unroll
    for (int mi = 0; mi < 4; mi++)
      a[mi] = *(const short8*)&a0[(wm + mi * 16 + l15) * BK + fswz];
#pragma unroll
    for (int ni = 0; ni < 4; ni++)
      b[ni] = *(const short8*)&b0[(wn + ni * 16 + l15) * BK + fswz];
#pragma unroll
    for (int mi = 0; mi < 4; mi++)
#pragma unroll
      for (int ni = 0; ni < 4; ni++)
        acc[mi][ni] = __builtin_amdgcn_mfma_f32_16x16x32_bf16(a[mi], b[ni], acc[mi][ni], 0, 0, 0);
  }

#pragma unroll
  for (int ni = 0; ni < 4; ni++) {
    int n = j0 + wn + ni * 16 + l15;
    float bv = bias[t * N + n];
#pragma unroll
    for (int mi = 0; mi < 4; mi++) {
      int mb = wm + mi * 16 + quad * 4;
#pragma unroll
      for (int r = 0; r < 4; r++) {
        int tok = toks[mb + r];
        if (tok >= 0) {
          float v = acc[mi][ni][r] + bv;
          if (GELU) {
            v = 0.5f * v * (1.f + erff(v * 0.70710678118654752f));
            Hout[(size_t)tok * N + n] = f2bf(v);
          } else {
            Fout[(size_t)tok * N + n] = v;
          }
        }
      }
    }
  }
}

// ================= fallback (round-1 kernels, used if ws too small) ==========
#define KPAD 40
__global__ __launch_bounds__(256) void gemm1_fb(
    const unsigned short* __restrict__ xb, const float* __restrict__ W1,
    const float* __restrict__ b1, const int* __restrict__ counts,
    const int* __restrict__ list, unsigned short* __restrict__ H) {
  int t = blockIdx.z;
  int count = counts[t];
  int base = blockIdx.y * BM;
  if (base >= count) return;
  int j0 = blockIdx.x * BN;
  __shared__ unsigned short As[BM][KPAD];
  __shared__ unsigned short Bs[BN][KPAD];
  __shared__ int toks[BM];
  int tid = threadIdx.x;
  if (tid < BM) {
    int slot = base + tid;
    toks[tid] = (slot < count) ? list[t * NTOK + slot] : -1;
  }
  __syncthreads();
  int arow = tid >> 1, acol = (tid & 1) * 16;
  int mytok = toks[arow];
  const unsigned short* xrow = xb + (size_t)(mytok < 0 ? 0 : mytok) * DC;
  int kg4 = (tid >> 5) * 4, ng4 = (tid & 31) * 4;
  const float* Wt = W1 + (size_t)t * DC * DH;
  int wid = tid >> 6, lane = tid & 63;
  int wm = (wid & 1) * 64, wn = (wid >> 1) * 64;
  int quad = lane >> 4, l15 = lane & 15;
  floatx4 acc[4][4];
#pragma unroll
  for (int mi = 0; mi < 4; mi++)
#pragma unroll
    for (int ni = 0; ni < 4; ni++) acc[mi][ni] = (floatx4){0.f, 0.f, 0.f, 0.f};
  for (int kt = 0; kt < DC / BK; kt++) {
    int k0 = kt * BK;
    if (mytok >= 0) {
      *(uint4*)&As[arow][acol]     = *(const uint4*)(xrow + k0 + acol);
      *(uint4*)&As[arow][acol + 8] = *(const uint4*)(xrow + k0 + acol + 8);
    } else {
      uint4 z = {0u,0u,0u,0u};
      *(uint4*)&As[arow][acol] = z; *(uint4*)&As[arow][acol + 8] = z;
    }
    const float* wb = Wt + (size_t)(k0 + kg4) * DH + j0 + ng4;
    float4 r0 = *(const float4*)(wb);
    float4 r1 = *(const float4*)(wb + DH);
    float4 r2 = *(const float4*)(wb + 2 * DH);
    float4 r3 = *(const float4*)(wb + 3 * DH);
    ushort4v c0 = { f2bf(r0.x), f2bf(r1.x), f2bf(r2.x), f2bf(r3.x) };
    ushort4v c1 = { f2bf(r0.y), f2bf(r1.y), f2bf(r2.y), f2bf(r3.y) };
    ushort4v c2 = { f2bf(r0.z), f2bf(r1.z), f2bf(r2.z), f2bf(r3.z) };
    ushort4v c3 = { f2bf(r0.w), f2bf(r1.w), f2bf(r2.w), f2bf(r3.w) };
    *(ushort4v*)&Bs[ng4 + 0][kg4] = c0; *(ushort4v*)&Bs[ng4 + 1][kg4] = c1;
    *(ushort4v*)&Bs[ng4 + 2][kg4] = c2; *(ushort4v*)&Bs[ng4 + 3][kg4] = c3;
    __syncthreads();
    short8 a[4], b[4];
#pragma unroll
    for (int mi = 0; mi < 4; mi++) a[mi] = *(const short8*)&As[wm + mi * 16 + l15][quad * 8];
#pragma unroll
    for (int ni = 0; ni < 4; ni++) b[ni] = *(const short8*)&Bs[wn + ni * 16 + l15][quad * 8];
#pragma unroll
    for (int mi = 0; mi < 4; mi++)
#pragma unroll
      for (int ni = 0; ni < 4; ni++)
        acc[mi][ni] = __builtin_amdgcn_mfma_f32_16x16x32_bf16(a[mi], b[ni], acc[mi][ni], 0, 0, 0);
    __syncthreads();
  }
#pragma unroll
  for (int ni = 0; ni < 4; ni++) {
    int n = j0 + wn + ni * 16 + l15;
    float bias = b1[t * DH + n];
#pragma unroll
    for (int mi = 0; mi < 4; mi++) {
      int mb = wm + mi * 16 + quad * 4;
#pragma unroll
      for (int r = 0; r < 4; r++) {
        int tok = toks[mb + r];
        if (tok >= 0) {
          float v = acc[mi][ni][r] + bias;
          v = 0.5f * v * (1.f + erff(v * 0.70710678118654752f));
          H[(size_t)tok * DH + n] = f2bf(v);
        }
      }
    }
  }
}

__global__ __launch_bounds__(256) void gemm2_fb(
    const unsigned short* __restrict__ H, const float* __restrict__ W2,
    const float* __restrict__ b2, const int* __restrict__ counts,
    const int* __restrict__ list, float* __restrict__ out) {
  int t = blockIdx.z;
  int count = counts[t];
  int base = blockIdx.y * BM;
  if (base >= count) return;
  int j0 = blockIdx.x * BN;
  __shared__ unsigned short As[BM][KPAD];
  __shared__ unsigned short Bs[BN][KPAD];
  __shared__ int toks[BM];
  int tid = threadIdx.x;
  if (tid < BM) {
    int slot = base + tid;
    toks[tid] = (slot < count) ? list[t * NTOK + slot] : -1;
  }
  __syncthreads();
  int arow = tid >> 1, acol = (tid & 1) * 16;
  int mytok = toks[arow];
  const unsigned short* hrow = H + (size_t)(mytok < 0 ? 0 : mytok) * DH;
  int kg4 = (tid >> 5) * 4, ng4 = (tid & 31) * 4;
  const float* Wt = W2 + (size_t)t * DH * DC;
  int wid = tid >> 6, lane = tid & 63;
  int wm = (wid & 1) * 64, wn = (wid >> 1) * 64;
  int quad = lane >> 4, l15 = lane & 15;
  floatx4 acc[4][4];
#pragma unroll
  for (int mi = 0; mi < 4; mi++)
#pragma unroll
    for (int ni = 0; ni < 4; ni++) acc[mi][ni] = (floatx4){0.f, 0.f, 0.f, 0.f};
  for (int kt = 0; kt < DH / BK; kt++) {
    int k0 = kt * BK;
    if (mytok >= 0) {
      *(uint4*)&As[arow][acol]     = *(const uint4*)(hrow + k0 + acol);
      *(uint4*)&As[arow][acol + 8] = *(const uint4*)(hrow + k0 + acol + 8);
    } else {
      uint4 z = {0u,0u,0u,0u};
      *(uint4*)&As[arow][acol] = z; *(uint4*)&As[arow][acol + 8] = z;
    }
    const float* wb = Wt + (size_t)(k0 + kg4) * DC + j0 + ng4;
    float4 r0 = *(const float4*)(wb);
    float4 r1 = *(const float4*)(wb + DC);
    float4 r2 = *(const float4*)(wb + 2 * DC);
    float4 r3 = *(const float4*)(wb + 3 * DC);
    ushort4v c0 = { f2bf(r0.x), f2bf(r1.x), f2bf(r2.x), f2bf(r3.x) };
    ushort4v c1 = { f2bf(r0.y), f2bf(r1.y), f2bf(r2.y), f2bf(r3.y) };
    ushort4v c2 = { f2bf(r0.z), f2bf(r1.z), f2bf(r2.z), f2bf(r3.z) };
    ushort4v c3 = { f2bf(r0.w), f2bf(r1.w), f2bf(r2.w), f2bf(r3.w) };
    *(ushort4v*)&Bs[ng4 + 0][kg4] = c0; *(ushort4v*)&Bs[ng4 + 1][kg4] = c1;
    *(ushort4v*)&Bs[ng4 + 2][kg4] = c2; *(ushort4v*)&Bs[ng4 + 3][kg4] = c3;
    __syncthreads();
    short8 a[4], b[4];
#pragma unroll
    for (int mi = 0; mi < 4; mi++) a[mi] = *(const short8*)&As[wm + mi * 16 + l15][quad * 8];
#pragma unroll
    for (int ni = 0; ni < 4; ni++) b[ni] = *(const short8*)&Bs[wn + ni * 16 + l15][quad * 8];
#pragma unroll
    for (int mi = 0; mi < 4; mi++)
#pragma unroll
      for (int ni = 0; ni < 4; ni++)
        acc[mi][ni] = __builtin_amdgcn_mfma_f32_16x16x32_bf16(a[mi], b[ni], acc[mi][ni], 0, 0, 0);
    __syncthreads();
  }
#pragma unroll
  for (int ni = 0; ni < 4; ni++) {
    int n = j0 + wn + ni * 16 + l15;
    float bias = b2[t * DC + n];
#pragma unroll
    for (int mi = 0; mi < 4; mi++) {
      int mb = wm + mi * 16 + quad * 4;
#pragma unroll
      for (int r = 0; r < 4; r++) {
        int tok = toks[mb + r];
        if (tok >= 0) out[(size_t)tok * DC + n] = acc[mi][ni][r] + bias;
      }
    }
  }
}

extern "C" void kernel_launch(void* const* d_in, const int* in_sizes, int n_in,
                              void* d_out, int out_size, void* d_ws, size_t ws_size,
                              hipStream_t stream) {
  const float* x        = (const float*)d_in[0];
  const float* pe       = (const float*)d_in[1];
  const float* pwp      = (const float*)d_in[2];
  const float* cwp      = (const float*)d_in[3];
  const float* pos_sigs = (const float*)d_in[4];
  const float* csigs    = (const float*)d_in[5];
  const float* W1       = (const float*)d_in[6];
  const float* b1       = (const float*)d_in[7];
  const float* W2       = (const float*)d_in[8];
  const float* b2       = (const float*)d_in[9];
  float* out = (float*)d_out;

  char* ws = (char*)d_ws;
  int* counts = (int*)ws;                       // 32 B
  int* list   = (int*)(ws + 1024);              // 256 KB
  int* best   = (int*)(ws + 300 * 1024);        // 32 KB @ [300K, 332K)
  unsigned short* xb = (unsigned short*)(ws + (1 << 20));  // 16 MB @ [1,17)

  // atomic-free routing: score -> stable compaction (writes counts + list)
  route_score<<<NTOK / 4, 256, 0, stream>>>(x, pe, pwp, cwp, pos_sigs, csigs,
                                            best, xb);
  route_compact<<<NT, 256, 0, stream>>>(best, counts, list);

  if (ws_size >= (size_t)145 * 1024 * 1024) {
    // fast path: WT @ [17,81) (reused for W1T then W2T), H @ [81,145)
    unsigned short* WT = (unsigned short*)(ws + ((size_t)17 << 20));
    unsigned short* H  = (unsigned short*)(ws + ((size_t)81 << 20));

    transpose_kernel<DC, DH><<<dim3(DH / 64, DC / 64, NT), 256, 0, stream>>>(W1, WT);
    // gemm1: unpinned 3D 3-buffer pipe (R3: 153us)
    gemm_pipe3d_kernel<DC, DH, true>
        <<<dim3(DH / BN, NTOK / BM, NT), 256, 0, stream>>>(
        xb, WT, b1, counts, list, H, nullptr);
    transpose_kernel<DH, DC><<<dim3(DC / 64, DH / 64, NT), 256, 0, stream>>>(W2, WT);
    // gemm2: XCD-pinned 1D 3-buffer pipe (R4: ~113us)
    gemm_pipe_kernel<DH, DC, DC / BN, false>
        <<<(DC / BN) * (NTOK / BM) * NT, 256, 0, stream>>>(
        H, WT, b2, counts, list, nullptr, out);
  } else {
    // fallback: round-1 structure, 96 MB footprint
    unsigned short* H = (unsigned short*)(ws + ((size_t)32 << 20));
    gemm1_fb<<<dim3(DH / BN, NTOK / BM, NT), 256, 0, stream>>>(xb, W1, b1, counts, list, H);
    gemm2_fb<<<dim3(DC / BN, NTOK / BM, NT), 256, 0, stream>>>(H, W2, b2, counts, list, out);
  }
}